// Round 9
// baseline (452.575 us; speedup 1.0000x reference)
//
#include <hip/hip_runtime.h>
#include <stdint.h>

// ---------- types ----------
typedef __attribute__((ext_vector_type(4))) int   int4v;   // 4 dwords = 16 int8
typedef __attribute__((ext_vector_type(4))) float f32x4;

#define K_DIM 4096
#define N_DIM 11008
#define M_DIM 8192
#define BM 256
#define BN 256
#define BKB 128             // K-bytes (= K elems, int8) per tile
#define NT (K_DIM / BKB)    // 32 K-tiles
#define MT2 (M_DIM / BM)    // 32
#define NT2 (N_DIM / BN)    // 43

// ---------- x quantization: per-row int8, s_r = max|x_row|/127 ----------
__global__ __launch_bounds__(256) void quant_x_kernel(
    const float* __restrict__ x, unsigned char* __restrict__ xq,
    float* __restrict__ srow)
{
    const int row = blockIdx.x;                       // 0..8191
    const float4* xr = (const float4*)(x + (size_t)row * K_DIM);
    float4 v[4];
    float m = 0.f;
    #pragma unroll
    for (int i = 0; i < 4; ++i) {
        v[i] = xr[threadIdx.x + 256 * i];
        m = fmaxf(m, fmaxf(fmaxf(fabsf(v[i].x), fabsf(v[i].y)),
                           fmaxf(fabsf(v[i].z), fabsf(v[i].w))));
    }
    #pragma unroll
    for (int off = 32; off; off >>= 1) m = fmaxf(m, __shfl_xor(m, off, 64));
    __shared__ float wmax[4];
    if ((threadIdx.x & 63) == 0) wmax[threadIdx.x >> 6] = m;
    __syncthreads();
    const float mb  = fmaxf(fmaxf(wmax[0], wmax[1]), fmaxf(wmax[2], wmax[3]));
    const float s   = (mb > 0.f) ? mb * (1.f / 127.f) : 1.f;
    const float inv = (mb > 0.f) ? 127.f / mb : 0.f;
    if (threadIdx.x == 0) srow[row] = s;
    uint32_t* oq = (uint32_t*)(xq + (size_t)row * K_DIM);
    #pragma unroll
    for (int i = 0; i < 4; ++i) {
        int a = __float2int_rn(v[i].x * inv), b = __float2int_rn(v[i].y * inv);
        int c = __float2int_rn(v[i].z * inv), d = __float2int_rn(v[i].w * inv);
        oq[threadIdx.x + 256 * i] =
            (a & 0xff) | ((b & 0xff) << 8) | ((c & 0xff) << 16) | ((d & 0xff) << 24);
    }
}

// ---------- w: int32 -> int8 (exact), 8/thread ----------
__global__ void cvt_w8_kernel(const int* __restrict__ w,
                              uint2* __restrict__ wq, int n8) {
    int i = blockIdx.x * blockDim.x + threadIdx.x;
    if (i >= n8) return;
    const int4* p = (const int4*)w + 2 * (size_t)i;
    int4 a = p[0], b = p[1];
    uint32_t lo = (a.x & 0xff) | ((a.y & 0xff) << 8) | ((a.z & 0xff) << 16) | ((a.w & 0xff) << 24);
    uint32_t hi = (b.x & 0xff) | ((b.y & 0xff) << 8) | ((b.z & 0xff) << 16) | ((b.w & 0xff) << 24);
    wq[i] = (uint2){lo, hi};
}

// ---------- 256x256 int8 GEMM, m201-faithful phase schedule ----------
#define GLDS16(gsrc, ldst)                                                       \
    __builtin_amdgcn_global_load_lds(                                            \
        (const __attribute__((address_space(1))) void*)(gsrc),                   \
        (__attribute__((address_space(3))) void*)(ldst), 16, 0, 0)

#define SCHED0()  __builtin_amdgcn_sched_barrier(0)
#define BARRIER() __builtin_amdgcn_s_barrier()
#define VMCNT(n)  asm volatile("s_waitcnt vmcnt(" #n ")" ::: "memory")
#define LGKM0()   do { asm volatile("s_waitcnt lgkmcnt(0)" ::: "memory"); SCHED0(); } while (0)
#define LGKM8()   do { asm volatile("s_waitcnt lgkmcnt(8)" ::: "memory"); SCHED0(); } while (0)

__global__ __launch_bounds__(512, 2) void gemm2_kernel(
    const unsigned char* __restrict__ xq,   // [8192][4096] int8
    const unsigned char* __restrict__ wq,   // [11008][4096] int8
    const float* __restrict__ srow,         // [8192] per-row x scale
    const float* __restrict__ scale,        // [1]
    const float* __restrict__ bias,         // [11008]
    float* __restrict__ out)                // [8192][11008]
{
    __shared__ unsigned char sm[131072];
    char* smc = (char*)sm;

    const int T  = threadIdx.x;
    const int l  = T & 63;
    const int wv = T >> 6;
    const int wm = wv >> 2;      // 0..1
    const int wn = wv & 3;       // 0..3

    // XCD-aware, bn-major grid map (B panel shared across XCDs via L3)
    const int orig = blockIdx.x;
    const int xcd  = orig & 7;
    const int p    = orig >> 3;          // 0..171
    const int bm   = xcd * 4 + (p & 3);  // 0..31
    const int bn   = p >> 2;             // 0..42
    const size_t rowM0 = (size_t)bm * BM;
    const size_t rowN0 = (size_t)bn * BN;

    // ---- staging precompute (pre-swizzled global source, linear LDS dest) ----
    const int rowT = T >> 3;                                          // 0..63
    const int colT = (((T & 7) * 16) ^ ((rowT & 7) << 4));            // BYTES
    const unsigned char* pAg = xq + (rowM0 + rowT) * (size_t)K_DIM + colT;
    const unsigned char* pBg = wq + (rowN0 + ((rowT >> 5) << 6) + (rowT & 31)) * (size_t)K_DIM + colT;

    auto stageA = [&](char* base, int Q, int kt) {
        #pragma unroll
        for (int c = 0; c < 2; ++c) {
            const unsigned char* src = pAg + (size_t)(c * 128 + Q * 64) * K_DIM + (size_t)kt * BKB;
            char* dst = base + Q * 16384 + c * 8192 + T * 16;
            GLDS16(src, dst);
        }
    };
    auto stageB = [&](char* base, int Q, int kt) {
        #pragma unroll
        for (int c = 0; c < 2; ++c) {
            const unsigned char* src = pBg + (size_t)(c * 128 + Q * 32) * K_DIM + (size_t)kt * BKB;
            char* dst = base + 32768 + Q * 16384 + c * 8192 + T * 16;
            GLDS16(src, dst);
        }
    };

    // ---- ds_read precompute (16x16x64 i8 fragments) ----
    const int sw     = (l & 7) << 4;
    const int inrow0 = (l >> 4) * 16;
    const int lowk0  = inrow0 ^ sw;            // k 0..63
    const int lowk1  = (64 + inrow0) ^ sw;     // k 64..127
    const int arow   = wm * 64 + (l & 15);
    const int brow   = wn * 32 + (l & 15);

    int4v acc[8][4];
    #pragma unroll
    for (int i = 0; i < 8; ++i)
        #pragma unroll
        for (int j = 0; j < 4; ++j)
            acc[i][j] = (int4v){0, 0, 0, 0};

    int4v Ah[4][2];   // current A quadrant (q0 at p0, q1 at p2)
    int4v Bh[4][2];   // Bh[0..1]=B0 (read p0), Bh[2..3]=B1 (read p1)

    char* const b0 = smc;
    char* const b1 = smc + 65536;

#define READ_A(base)                                                             \
    _Pragma("unroll")                                                            \
    for (int im = 0; im < 4; ++im) {                                             \
        Ah[im][0] = *(const int4v*)((base) + (arow + im * 16) * 128 + lowk0);    \
        Ah[im][1] = *(const int4v*)((base) + (arow + im * 16) * 128 + lowk1);    \
    }
#define READ_B(base, f0)                                                         \
    _Pragma("unroll")                                                            \
    for (int f = 0; f < 2; ++f) {                                                \
        Bh[(f0) + f][0] = *(const int4v*)((base) + (brow + f * 16) * 128 + lowk0); \
        Bh[(f0) + f][1] = *(const int4v*)((base) + (brow + f * 16) * 128 + lowk1); \
    }
#define MFMAQ(mi, ni)                                                            \
    __builtin_amdgcn_s_setprio(1);                                               \
    _Pragma("unroll")                                                            \
    for (int im = 0; im < 4; ++im)                                               \
        _Pragma("unroll")                                                        \
        for (int jn = 0; jn < 2; ++jn)                                           \
            _Pragma("unroll")                                                    \
            for (int kk = 0; kk < 2; ++kk)                                       \
                acc[(mi) + im][(ni) + jn] = __builtin_amdgcn_mfma_i32_16x16x64_i8( \
                    Ah[im][kk], Bh[(ni) + jn][kk], acc[(mi) + im][(ni) + jn], 0, 0, 0); \
    __builtin_amdgcn_s_setprio(0);

    // m201-faithful tile: 4 phases, each {reads||stage; BAR; lgkmcnt(0); MFMA; BAR}.
    // Stage-into-dead-region: A0@p1 (read p0), B0@p2 (read p0), B1+A1@p3 (read p1/p2).
    // Boundary gate vmcnt(8): 8 outstanding = this tile's stages (E+2); proves E+1 resident.
#define TILE_BODY(bcur, EE, STN)                                                 \
    /* p0 */                                                                     \
    READ_A(bcur);                                                                \
    READ_B((bcur) + 32768, 0);                                                   \
    LGKM8();                                                                     \
    BARRIER(); SCHED0();                                                         \
    LGKM0();                                                                     \
    MFMAQ(0, 0);                                                                 \
    BARRIER(); SCHED0();                                                         \
    /* p1 */                                                                     \
    READ_B((bcur) + 32768 + 16384, 2);                                           \
    if (STN) stageA((bcur), 0, (EE) + 2);                                        \
    BARRIER(); SCHED0();                                                         \
    LGKM0();                                                                     \
    MFMAQ(0, 2);                                                                 \
    BARRIER(); SCHED0();                                                         \
    /* p2 */                                                                     \
    READ_A((bcur) + 16384);                                                      \
    if (STN) stageB((bcur), 0, (EE) + 2);                                        \
    BARRIER(); SCHED0();                                                         \
    LGKM0();                                                                     \
    MFMAQ(4, 0);                                                                 \
    BARRIER(); SCHED0();                                                         \
    /* p3 */                                                                     \
    if (STN) { stageB((bcur), 1, (EE) + 2); stageA((bcur), 1, (EE) + 2); }       \
    BARRIER(); SCHED0();                                                         \
    MFMAQ(4, 2);                                                                 \
    if (STN) VMCNT(8); else VMCNT(0);                                            \
    BARRIER(); SCHED0();

    // ---- prologue: tile0 (8) + tile1 (8) ----
    stageA(b0, 0, 0); stageB(b0, 0, 0); stageB(b0, 1, 0); stageA(b0, 1, 0);
    stageA(b1, 0, 1); stageB(b1, 0, 1); stageB(b1, 1, 1); stageA(b1, 1, 1);
    VMCNT(8);                        // tile 0 resident
    BARRIER(); SCHED0();

    for (int kt2 = 0; kt2 < NT / 2; ++kt2) {
        const int  E   = kt2 * 2;
        const bool st0 = (E + 2 < NT);
        const bool st1 = (E + 3 < NT);
        TILE_BODY(b0, E,     st0);
        TILE_BODY(b1, E + 1, st1);
    }

    // ---- epilogue: y = acc * s_r * s_w + bias ----
    const float s = scale[0];
    #pragma unroll
    for (int fm = 0; fm < 8; ++fm) {
        const size_t row0 = rowM0 + wm * 128 + fm * 16 + (l >> 4) * 4;
        const float4 sr4 = *(const float4*)(srow + row0);
        #pragma unroll
        for (int fn = 0; fn < 4; ++fn) {
            const int col = (int)rowN0 + wn * 64 + fn * 16 + (l & 15);
            const float bv = bias[col];
            float* o = out + row0 * N_DIM + col;
            o[0]                  = (float)acc[fm][fn][0] * (sr4.x * s) + bv;
            o[(size_t)1 * N_DIM]  = (float)acc[fm][fn][1] * (sr4.y * s) + bv;
            o[(size_t)2 * N_DIM]  = (float)acc[fm][fn][2] * (sr4.z * s) + bv;
            o[(size_t)3 * N_DIM]  = (float)acc[fm][fn][3] * (sr4.w * s) + bv;
        }
    }
}

// ---------- launch ----------
extern "C" void kernel_launch(void* const* d_in, const int* in_sizes, int n_in,
                              void* d_out, int out_size, void* d_ws, size_t ws_size,
                              hipStream_t stream) {
    const float* x     = (const float*)d_in[0];
    const int*   w     = (const int*)d_in[1];
    const float* scale = (const float*)d_in[2];
    const float* bias  = (const float*)d_in[3];
    float*       out   = (float*)d_out;

    const size_t x_elems = (size_t)M_DIM * K_DIM;    // 33,554,432
    const size_t w_elems = (size_t)N_DIM * K_DIM;    // 45,088,768
    const size_t xq_off  = 0;
    const size_t wq_off  = x_elems;                  // bytes (int8)
    const size_t sr_off  = x_elems + w_elems;
    if (ws_size < sr_off + (size_t)M_DIM * 4) return;

    unsigned char* xqp = (unsigned char*)d_ws + xq_off;
    unsigned char* wqp = (unsigned char*)d_ws + wq_off;
    float*         srp = (float*)((unsigned char*)d_ws + sr_off);

    quant_x_kernel<<<M_DIM, 256, 0, stream>>>(x, xqp, srp);
    {
        int n8 = (int)(w_elems / 8);
        cvt_w8_kernel<<<(n8 + 255) / 256, 256, 0, stream>>>(w, (uint2*)wqp, n8);
    }
    gemm2_kernel<<<MT2 * NT2, 512, 0, stream>>>(xqp, wqp, srp, scale, bias, out);
}